// Round 8
// baseline (927.465 us; speedup 1.0000x reference)
//
#include <hip/hip_runtime.h>

// STGNN K-hop propagation, CSR-by-destination, D-SLAB execution.
//   norm[e] = deginv[row[e]]*deginv[col[e]]
//   b = sum_in norm*ef            (b_kernel: ef CSR-gather, unroll-4 MLP)
//   hop h, slab s (6 x 64B slabs): xk[:,s] = S*x_{h-1}[:,s] + b[:,s]
//       out[:,s] (init h0*x+h1*x1 at h=1, += hk*xk after)
// WHY SLABS: x-gathers hit a 19.2MB buffer that cannot fit a 4MiB XCD L2 ->
// random-line service at ~1.8TB/s effective was the bound (R4-R7: occupancy,
// coalescing, sorting all neutral). One slab = 3.2MB window -> L2-resident.
// Kernels in one stream serialize, so concurrency never spans slabs.
// Streaming traffic (edat/b/out/xnext) uses NT loads/stores to not evict the
// x-window. Internal hop buffers are SLAB-MAJOR [6][N][16f] so each window is
// contiguous; b/out stay node-major (strided-64B NT streams).

#define CH 24   // float4 chunks per 96-float row

typedef float v4f __attribute__((ext_vector_type(4)));
typedef float v2f __attribute__((ext_vector_type(2)));

__global__ void deg_kernel(const int* __restrict__ col, int* __restrict__ deg, int E) {
    int e = blockIdx.x * blockDim.x + threadIdx.x;
    if (e < E) atomicAdd(&deg[col[e]], 1);
}

__global__ void deginv_kernel(const int* __restrict__ deg, float* __restrict__ deginv, int n) {
    int i = blockIdx.x * blockDim.x + threadIdx.x;
    if (i < n) {
        int d = deg[i];
        deginv[i] = (d > 0) ? rsqrtf((float)d) : 0.0f;
    }
}

// ---- hierarchical exclusive scan: 1024 elems/block ----
__global__ __launch_bounds__(256) void scan1_kernel(const int* __restrict__ deg,
                                                    int* __restrict__ starts,
                                                    int* __restrict__ bsums, int n) {
    int t = threadIdx.x;
    int i = blockIdx.x * 1024 + t * 4;
    int4 v = make_int4(0, 0, 0, 0);
    if (i + 3 < n) v = *(const int4*)(deg + i);
    else {
        if (i + 0 < n) v.x = deg[i + 0];
        if (i + 1 < n) v.y = deg[i + 1];
        if (i + 2 < n) v.z = deg[i + 2];
        if (i + 3 < n) v.w = deg[i + 3];
    }
    int s0 = v.x, s1 = s0 + v.y, s2 = s1 + v.z, s3 = s2 + v.w;
    int tot = s3;
    int lane = t & 63;
    int incl = tot;
    for (int off = 1; off < 64; off <<= 1) {
        int u = __shfl_up(incl, off, 64);
        if (lane >= off) incl += u;
    }
    __shared__ int wsum[4];
    __shared__ int woff[4];
    int wid = t >> 6;
    if (lane == 63) wsum[wid] = incl;
    __syncthreads();
    if (t == 0) { int a = 0; for (int w = 0; w < 4; ++w) { woff[w] = a; a += wsum[w]; } }
    __syncthreads();
    int excl = incl - tot + woff[wid];
    if (i + 0 < n) starts[i + 0] = excl;
    if (i + 1 < n) starts[i + 1] = excl + s0;
    if (i + 2 < n) starts[i + 2] = excl + s1;
    if (i + 3 < n) starts[i + 3] = excl + s2;
    if (t == 255) bsums[blockIdx.x] = woff[3] + wsum[3];
}

__global__ __launch_bounds__(64) void scan2_kernel(int* __restrict__ bsums, int nb,
                                                   int* __restrict__ starts, int n, int total) {
    int lane = threadIdx.x;
    int v = (lane < nb) ? bsums[lane] : 0;
    int incl = v;
    for (int off = 1; off < 64; off <<= 1) {
        int u = __shfl_up(incl, off, 64);
        if (lane >= off) incl += u;
    }
    if (lane < nb) bsums[lane] = incl - v;
    if (lane == 0) starts[n] = total;
}

__global__ __launch_bounds__(256) void scan3_kernel(int* __restrict__ starts,
                                                    int* __restrict__ cursor,
                                                    const int* __restrict__ bsums, int n) {
    int t = threadIdx.x;
    int i = blockIdx.x * 1024 + t * 4;
    int off = bsums[blockIdx.x];
    for (int k = 0; k < 4; ++k) {
        int ii = i + k;
        if (ii < n) {
            int s = starts[ii] + off;
            starts[ii] = s;
            cursor[ii] = s;
        }
    }
}

// Fused fill+slot: place edge in CSR slot AND write (row, norm) metadata in one pass.
__global__ void fill_kernel(const int* __restrict__ col, const int* __restrict__ row,
                            const float* __restrict__ deginv, int* __restrict__ cursor,
                            int* __restrict__ eids, float2* __restrict__ edat, int E) {
    int e = blockIdx.x * blockDim.x + threadIdx.x;
    if (e < E) {
        int c = col[e], r = row[e];
        int pos = atomicAdd(&cursor[c], 1);
        eids[pos] = e;
        float2 o;
        o.x = __int_as_float(r);
        o.y = deginv[r] * deginv[c];
        edat[pos] = o;
    }
}

// b = sum norm*ef over CSR segment. 12 thr/node (chunks c, c+12), unroll-4:
// 8 NT 16B loads in flight per thread against the compulsory 307MB HBM gather.
__global__ __launch_bounds__(256) void b_kernel(const int* __restrict__ starts,
                                                const float2* __restrict__ edat,
                                                const int* __restrict__ eids,
                                                const float4* __restrict__ ef4,
                                                float4* __restrict__ bvec4,
                                                int NC12) {
    int g = blockIdx.x * 256 + threadIdx.x;
    if (g >= NC12) return;
    int node = g / 12;
    int c = g - node * 12;
    int s = starts[node], e_end = starts[node + 1];
    v4f ab0 = (v4f)(0.f), ab1 = (v4f)(0.f);
    int j = s;
    for (; j + 4 <= e_end; j += 4) {
        float2 a0 = edat[j], a1 = edat[j + 1], a2 = edat[j + 2], a3 = edat[j + 3];
        int e0 = eids[j], e1 = eids[j + 1], e2 = eids[j + 2], e3 = eids[j + 3];
        const v4f* p0 = (const v4f*)(ef4 + (size_t)e0 * CH + c);
        const v4f* p1 = (const v4f*)(ef4 + (size_t)e1 * CH + c);
        const v4f* p2 = (const v4f*)(ef4 + (size_t)e2 * CH + c);
        const v4f* p3 = (const v4f*)(ef4 + (size_t)e3 * CH + c);
        v4f f00 = __builtin_nontemporal_load(p0);
        v4f f01 = __builtin_nontemporal_load(p0 + 12);
        v4f f10 = __builtin_nontemporal_load(p1);
        v4f f11 = __builtin_nontemporal_load(p1 + 12);
        v4f f20 = __builtin_nontemporal_load(p2);
        v4f f21 = __builtin_nontemporal_load(p2 + 12);
        v4f f30 = __builtin_nontemporal_load(p3);
        v4f f31 = __builtin_nontemporal_load(p3 + 12);
        ab0 += a0.y * f00 + a1.y * f10 + a2.y * f20 + a3.y * f30;
        ab1 += a0.y * f01 + a1.y * f11 + a2.y * f21 + a3.y * f31;
    }
    for (; j < e_end; ++j) {
        float2 a = edat[j];
        int e = eids[j];
        const v4f* p = (const v4f*)(ef4 + (size_t)e * CH + c);
        v4f f0 = __builtin_nontemporal_load(p);
        v4f f1 = __builtin_nontemporal_load(p + 12);
        ab0 += a.y * f0;
        ab1 += a.y * f1;
    }
    v4f* bp = (v4f*)(bvec4 + (size_t)node * CH + c);
    bp[0] = ab0;
    bp[12] = ab1;
}

// One hop, one 64B slab. 4 thr/node, thread k owns float4 k of the slab.
// xprev: base pre-offset by slab on host; row stride pstride float4s
//   (24 = node-major x for hop1, 4 = slab-major buf for hops 2+).
// Gathers are NORMAL loads (cacheable; 3.2MB window -> L2-resident).
// Everything else is NT so it cannot evict the window.
__global__ __launch_bounds__(256) void slab_kernel(const int* __restrict__ starts,
                                                   const float2* __restrict__ edat,
                                                   const float4* __restrict__ xprev4,
                                                   int pstride,
                                                   const float4* __restrict__ bvec4,
                                                   float4* __restrict__ xnext4,
                                                   int writeNext,
                                                   float4* __restrict__ out4,
                                                   const float* __restrict__ hopwise,
                                                   int hop, int isFirst, int NC4) {
    int g = blockIdx.x * 256 + threadIdx.x;
    if (g >= NC4) return;
    int node = g >> 2;
    int k = g & 3;
    int s = starts[node], e_end = starts[node + 1];
    const v4f* xp = (const v4f*)xprev4;
    v4f ax = (v4f)(0.f);
    int j = s;
    for (; j + 4 <= e_end; j += 4) {
        const v2f* ap = (const v2f*)(edat + j);
        v2f a0 = __builtin_nontemporal_load(ap);
        v2f a1 = __builtin_nontemporal_load(ap + 1);
        v2f a2 = __builtin_nontemporal_load(ap + 2);
        v2f a3 = __builtin_nontemporal_load(ap + 3);
        int r0 = __float_as_int(a0.x), r1 = __float_as_int(a1.x);
        int r2 = __float_as_int(a2.x), r3 = __float_as_int(a3.x);
        v4f v0 = xp[(size_t)r0 * pstride + k];
        v4f v1 = xp[(size_t)r1 * pstride + k];
        v4f v2 = xp[(size_t)r2 * pstride + k];
        v4f v3 = xp[(size_t)r3 * pstride + k];
        ax += a0.y * v0 + a1.y * v1 + a2.y * v2 + a3.y * v3;
    }
    for (; j < e_end; ++j) {
        v2f a = __builtin_nontemporal_load((const v2f*)(edat + j));
        int r = __float_as_int(a.x);
        ax += a.y * xp[(size_t)r * pstride + k];
    }
    size_t ob = (size_t)node * CH + k;          // node-major chunk (base pre-offset)
    v4f b = __builtin_nontemporal_load((const v4f*)(bvec4 + ob));
    v4f xv = ax + b;
    if (writeNext)
        __builtin_nontemporal_store(xv, (v4f*)(xnext4 + (size_t)node * 4 + k));
    if (isFirst) {
        float h0 = hopwise[0], h1 = hopwise[1];
        v4f xs = xp[(size_t)node * pstride + k];   // self row: inside the window
        v4f ov = h0 * xs + h1 * xv;
        __builtin_nontemporal_store(ov, (v4f*)(out4 + ob));
    } else {
        float h = hopwise[hop];
        v4f ov = __builtin_nontemporal_load((const v4f*)(out4 + ob));
        ov += h * xv;
        __builtin_nontemporal_store(ov, (v4f*)(out4 + ob));
    }
}

extern "C" void kernel_launch(void* const* d_in, const int* in_sizes, int n_in,
                              void* d_out, int out_size, void* d_ws, size_t ws_size,
                              hipStream_t stream) {
    const float* x       = (const float*)d_in[0];
    const float* ef      = (const float*)d_in[1];
    const float* hopwise = (const float*)d_in[2];
    const int*   eidx    = (const int*)d_in[3];

    const int E = in_sizes[3] / 2;
    const int D = in_sizes[1] / E;          // 96
    const int N = in_sizes[0] / D;          // 50000
    const int K = in_sizes[2] - 1;          // 3
    const int NSLAB = 6;                    // 6 x 64B slabs (16 floats)
    const int NC12 = N * 12;
    const int NC4  = N * 4;

    const int* row = eidx;
    const int* col = eidx + E;
    float* out = (float*)d_out;

    // Workspace layout (N even, E multiple of 4 -> 16B alignment holds)
    char* w = (char*)d_ws;
    int*    deg    = (int*)w;     w += (size_t)N * 4;
    int*    starts = (int*)w;     w += (size_t)(N + 8) * 4;
    int*    cursor = (int*)w;     w += (size_t)N * 4;
    int*    eids   = (int*)w;     w += (size_t)E * 4;
    float*  deginv = (float*)w;   w += (size_t)N * 4;
    int*    bsums  = (int*)w;     w += 256 * 4;
    float2* edat   = (float2*)w;  w += (size_t)E * 8;
    float*  bvec   = (float*)w;   w += (size_t)N * D * 4;   // node-major
    float*  buf0   = (float*)w;   w += (size_t)N * D * 4;   // slab-major [6][N][16]
    float*  buf1   = (float*)w;   /* w += N*D*4 */          // slab-major

    const int BT = 256;
    const int nScanBlocks = (N + 1023) / 1024;

    // CSR build
    hipMemsetAsync(deg, 0, (size_t)N * sizeof(int), stream);
    deg_kernel<<<(E + BT - 1) / BT, BT, 0, stream>>>(col, deg, E);
    deginv_kernel<<<(N + BT - 1) / BT, BT, 0, stream>>>(deg, deginv, N);
    scan1_kernel<<<nScanBlocks, 256, 0, stream>>>(deg, starts, bsums, N);
    scan2_kernel<<<1, 64, 0, stream>>>(bsums, nScanBlocks, starts, N, E);
    scan3_kernel<<<nScanBlocks, 256, 0, stream>>>(starts, cursor, bsums, N);
    fill_kernel<<<(E + BT - 1) / BT, BT, 0, stream>>>(col, row, deginv, cursor, eids, edat, E);

    // b = sum norm*ef (compulsory HBM gather, max MLP)
    b_kernel<<<(NC12 + 255) / 256, 256, 0, stream>>>(starts, edat, eids,
                                                     (const float4*)ef, (float4*)bvec, NC12);

    // hops: 6 L2-resident slab passes each, sequential launches
    int slabBlocks = (NC4 + 255) / 256;
    const float* xcur = buf0;   // tracks slab-major current buffer for hops>=2
    for (int hop = 1; hop <= K; ++hop) {
        const float* xprev;
        int pstride;
        float* xnext;
        if (hop == 1) { xprev = x; pstride = CH; xnext = buf0; }
        else {
            xprev = xcur; pstride = 4;
            xnext = (xcur == buf0) ? buf1 : buf0;
        }
        int writeNext = (hop < K) ? 1 : 0;
        for (int s = 0; s < NSLAB; ++s) {
            const float4* xprev4 = (const float4*)xprev +
                ((hop == 1) ? (size_t)s * 4 : (size_t)s * N * 4);
            float4* xnext4 = (float4*)xnext + (size_t)s * N * 4;
            slab_kernel<<<slabBlocks, 256, 0, stream>>>(
                starts, edat, xprev4, pstride,
                (const float4*)bvec + (size_t)s * 4,
                xnext4, writeNext,
                (float4*)out + (size_t)s * 4,
                hopwise, hop, (hop == 1) ? 1 : 0, NC4);
        }
        if (hop >= 1) xcur = (hop == 1) ? buf0 : xnext;
    }
}

// Round 10
// 658.390 us; speedup vs baseline: 1.4087x; 1.4087x over previous
//
#include <hip/hip_runtime.h>

// STGNN K-hop propagation, CSR-by-destination, FP16 GATHER OPERANDS.
//   norm[e] = deginv[row[e]]*deginv[col[e]]
//   b[n,:]  = sum_in norm*ef      (hop-invariant, computed inside fused hop1)
//   hop1 (fused): x1 = S*xh + b; out = h0*x(f32) + h1*x1; bvec = b
//   hops 2..K:    xk = S*xh_{k-1} + b; out += hk*xk
// WHY FP16: hops are bound by random 64B-line service (~1.8TB/s effective;
// R4-R8: occupancy/coalescing/sorting/slabbing all neutral-or-worse). fp16
// storage halves lines/row (384B->192B = 3 lines) => half the line traffic.
// ALL accumulation stays f32; only the gathered operand is rounded (adds
// ~1e-3 abs error vs the 0.0156 systematic baseline).
// Mapping: 12 thr/node; thread c owns halves [8c,8c+8) = f32 chunks {2c,2c+1}.

#define CH 24    // float4 chunks per 96-float row
#define CHH 12   // h8 (16B) chunks per 96-half row

typedef float v4f __attribute__((ext_vector_type(4)));
typedef float v8f __attribute__((ext_vector_type(8)));
typedef _Float16 h8 __attribute__((ext_vector_type(8)));

__global__ void deg_kernel(const int* __restrict__ col, int* __restrict__ deg, int E) {
    int e = blockIdx.x * blockDim.x + threadIdx.x;
    if (e < E) atomicAdd(&deg[col[e]], 1);
}

__global__ void deginv_kernel(const int* __restrict__ deg, float* __restrict__ deginv, int n) {
    int i = blockIdx.x * blockDim.x + threadIdx.x;
    if (i < n) {
        int d = deg[i];
        deginv[i] = (d > 0) ? rsqrtf((float)d) : 0.0f;
    }
}

// ---- hierarchical exclusive scan: 1024 elems/block ----
__global__ __launch_bounds__(256) void scan1_kernel(const int* __restrict__ deg,
                                                    int* __restrict__ starts,
                                                    int* __restrict__ bsums, int n) {
    int t = threadIdx.x;
    int i = blockIdx.x * 1024 + t * 4;
    int4 v = make_int4(0, 0, 0, 0);
    if (i + 3 < n) v = *(const int4*)(deg + i);
    else {
        if (i + 0 < n) v.x = deg[i + 0];
        if (i + 1 < n) v.y = deg[i + 1];
        if (i + 2 < n) v.z = deg[i + 2];
        if (i + 3 < n) v.w = deg[i + 3];
    }
    int s0 = v.x, s1 = s0 + v.y, s2 = s1 + v.z, s3 = s2 + v.w;
    int tot = s3;
    int lane = t & 63;
    int incl = tot;
    for (int off = 1; off < 64; off <<= 1) {
        int u = __shfl_up(incl, off, 64);
        if (lane >= off) incl += u;
    }
    __shared__ int wsum[4];
    __shared__ int woff[4];
    int wid = t >> 6;
    if (lane == 63) wsum[wid] = incl;
    __syncthreads();
    if (t == 0) { int a = 0; for (int w = 0; w < 4; ++w) { woff[w] = a; a += wsum[w]; } }
    __syncthreads();
    int excl = incl - tot + woff[wid];
    if (i + 0 < n) starts[i + 0] = excl;
    if (i + 1 < n) starts[i + 1] = excl + s0;
    if (i + 2 < n) starts[i + 2] = excl + s1;
    if (i + 3 < n) starts[i + 3] = excl + s2;
    if (t == 255) bsums[blockIdx.x] = woff[3] + wsum[3];
}

__global__ __launch_bounds__(64) void scan2_kernel(int* __restrict__ bsums, int nb,
                                                   int* __restrict__ starts, int n, int total) {
    int lane = threadIdx.x;
    int v = (lane < nb) ? bsums[lane] : 0;
    int incl = v;
    for (int off = 1; off < 64; off <<= 1) {
        int u = __shfl_up(incl, off, 64);
        if (lane >= off) incl += u;
    }
    if (lane < nb) bsums[lane] = incl - v;
    if (lane == 0) starts[n] = total;
}

__global__ __launch_bounds__(256) void scan3_kernel(int* __restrict__ starts,
                                                    int* __restrict__ cursor,
                                                    const int* __restrict__ bsums, int n) {
    int t = threadIdx.x;
    int i = blockIdx.x * 1024 + t * 4;
    int off = bsums[blockIdx.x];
    for (int k = 0; k < 4; ++k) {
        int ii = i + k;
        if (ii < n) {
            int s = starts[ii] + off;
            starts[ii] = s;
            cursor[ii] = s;
        }
    }
}

// Fused fill+slot: place edge in CSR slot AND write (row, norm) metadata in one pass.
__global__ void fill_kernel(const int* __restrict__ col, const int* __restrict__ row,
                            const float* __restrict__ deginv, int* __restrict__ cursor,
                            int* __restrict__ eids, float2* __restrict__ edat, int E) {
    int e = blockIdx.x * blockDim.x + threadIdx.x;
    if (e < E) {
        int c = col[e], r = row[e];
        int pos = atomicAdd(&cursor[c], 1);
        eids[pos] = e;
        float2 o;
        o.x = __int_as_float(r);
        o.y = deginv[r] * deginv[c];
        edat[pos] = o;
    }
}

// x (f32 node-major) -> xh (fp16 node-major). g = node*12+c -> float4 idx 2g,2g+1.
__global__ __launch_bounds__(256) void cvt_kernel(const float4* __restrict__ x4,
                                                  h8* __restrict__ xh, int total) {
    int g = blockIdx.x * 256 + threadIdx.x;
    if (g >= total) return;
    float4 a = x4[2 * g], b = x4[2 * g + 1];
    h8 o;
    o[0] = (_Float16)a.x; o[1] = (_Float16)a.y; o[2] = (_Float16)a.z; o[3] = (_Float16)a.w;
    o[4] = (_Float16)b.x; o[5] = (_Float16)b.y; o[6] = (_Float16)b.z; o[7] = (_Float16)b.w;
    xh[g] = o;
}

// Fused hop1: b = sum norm*ef (f32 nt gather); x1 = sum norm*xh[row] + b;
// out = h0*x(f32 exact) + h1*x1; bvec = b; xh_next = fp16(x1).
__global__ __launch_bounds__(256) void hop1_kernel(const int* __restrict__ starts,
                                                   const float2* __restrict__ edat,
                                                   const int* __restrict__ eids,
                                                   const float4* __restrict__ ef4,
                                                   const h8* __restrict__ xh,
                                                   const float4* __restrict__ x4,
                                                   float4* __restrict__ bvec4,
                                                   h8* __restrict__ xhnext,
                                                   float4* __restrict__ out4,
                                                   const float* __restrict__ hopwise,
                                                   int NC12) {
    int g = blockIdx.x * 256 + threadIdx.x;
    if (g >= NC12) return;
    int node = g / CHH;
    int c = g - node * CHH;
    int s = starts[node], e_end = starts[node + 1];
    v8f ab = (v8f)(0.f);
    v8f ax = (v8f)(0.f);
    int j = s;
    for (; j + 2 <= e_end; j += 2) {
        float2 a0 = edat[j], a1 = edat[j + 1];
        int e0 = eids[j], e1 = eids[j + 1];
        int r0 = __float_as_int(a0.x), r1 = __float_as_int(a1.x);
        const v4f* fp0 = (const v4f*)(ef4 + (size_t)e0 * CH + 2 * c);
        const v4f* fp1 = (const v4f*)(ef4 + (size_t)e1 * CH + 2 * c);
        v4f f00 = __builtin_nontemporal_load(fp0);
        v4f f01 = __builtin_nontemporal_load(fp0 + 1);
        v4f f10 = __builtin_nontemporal_load(fp1);
        v4f f11 = __builtin_nontemporal_load(fp1 + 1);
        h8 hv0 = xh[(size_t)r0 * CHH + c];
        h8 hv1 = xh[(size_t)r1 * CHH + c];
        v8f fv0 = (v8f){f00.x, f00.y, f00.z, f00.w, f01.x, f01.y, f01.z, f01.w};
        v8f fv1 = (v8f){f10.x, f10.y, f10.z, f10.w, f11.x, f11.y, f11.z, f11.w};
        ab += a0.y * fv0 + a1.y * fv1;
        ax += a0.y * __builtin_convertvector(hv0, v8f)
            + a1.y * __builtin_convertvector(hv1, v8f);
    }
    for (; j < e_end; ++j) {
        float2 a = edat[j];
        int e = eids[j];
        int r = __float_as_int(a.x);
        const v4f* fp = (const v4f*)(ef4 + (size_t)e * CH + 2 * c);
        v4f f0 = __builtin_nontemporal_load(fp);
        v4f f1 = __builtin_nontemporal_load(fp + 1);
        h8 hv = xh[(size_t)r * CHH + c];
        v8f fv = (v8f){f0.x, f0.y, f0.z, f0.w, f1.x, f1.y, f1.z, f1.w};
        ab += a.y * fv;
        ax += a.y * __builtin_convertvector(hv, v8f);
    }
    float h0 = hopwise[0], h1 = hopwise[1];
    size_t o = (size_t)node * CH + 2 * c;
    bvec4[o]     = make_float4(ab[0], ab[1], ab[2], ab[3]);
    bvec4[o + 1] = make_float4(ab[4], ab[5], ab[6], ab[7]);
    v8f x1 = ax + ab;
    xhnext[(size_t)node * CHH + c] = __builtin_convertvector(x1, h8);
    float4 xs0 = x4[o], xs1 = x4[o + 1];
    float4 ov0, ov1;
    ov0.x = h0 * xs0.x + h1 * x1[0]; ov0.y = h0 * xs0.y + h1 * x1[1];
    ov0.z = h0 * xs0.z + h1 * x1[2]; ov0.w = h0 * xs0.w + h1 * x1[3];
    ov1.x = h0 * xs1.x + h1 * x1[4]; ov1.y = h0 * xs1.y + h1 * x1[5];
    ov1.z = h0 * xs1.z + h1 * x1[6]; ov1.w = h0 * xs1.w + h1 * x1[7];
    out4[o] = ov0; out4[o + 1] = ov1;
}

// hops 2..K: xk = S*xh_{k-1} + b; out += hk*xk.  writeNext=0 on the last hop.
__global__ __launch_bounds__(256) void hop_kernel(const int* __restrict__ starts,
                                                  const float2* __restrict__ edat,
                                                  const h8* __restrict__ xhcur,
                                                  const float4* __restrict__ bvec4,
                                                  h8* __restrict__ xhnext,
                                                  float4* __restrict__ out4,
                                                  const float* __restrict__ hopwise,
                                                  int hop, int writeNext, int NC12) {
    int g = blockIdx.x * 256 + threadIdx.x;
    if (g >= NC12) return;
    int node = g / CHH;
    int c = g - node * CHH;
    int s = starts[node], e_end = starts[node + 1];
    v8f ax = (v8f)(0.f);
    int j = s;
    for (; j + 4 <= e_end; j += 4) {
        float2 a0 = edat[j], a1 = edat[j + 1], a2 = edat[j + 2], a3 = edat[j + 3];
        int r0 = __float_as_int(a0.x), r1 = __float_as_int(a1.x);
        int r2 = __float_as_int(a2.x), r3 = __float_as_int(a3.x);
        h8 v0 = xhcur[(size_t)r0 * CHH + c];
        h8 v1 = xhcur[(size_t)r1 * CHH + c];
        h8 v2 = xhcur[(size_t)r2 * CHH + c];
        h8 v3 = xhcur[(size_t)r3 * CHH + c];
        ax += a0.y * __builtin_convertvector(v0, v8f)
            + a1.y * __builtin_convertvector(v1, v8f)
            + a2.y * __builtin_convertvector(v2, v8f)
            + a3.y * __builtin_convertvector(v3, v8f);
    }
    for (; j < e_end; ++j) {
        float2 a = edat[j];
        int r = __float_as_int(a.x);
        h8 v = xhcur[(size_t)r * CHH + c];
        ax += a.y * __builtin_convertvector(v, v8f);
    }
    float h = hopwise[hop];
    size_t o = (size_t)node * CH + 2 * c;
    float4 b0 = bvec4[o], b1 = bvec4[o + 1];
    v8f bv = (v8f){b0.x, b0.y, b0.z, b0.w, b1.x, b1.y, b1.z, b1.w};
    v8f xv = ax + bv;
    if (writeNext)
        xhnext[(size_t)node * CHH + c] = __builtin_convertvector(xv, h8);
    float4 ov0 = out4[o], ov1 = out4[o + 1];
    ov0.x += h * xv[0]; ov0.y += h * xv[1]; ov0.z += h * xv[2]; ov0.w += h * xv[3];
    ov1.x += h * xv[4]; ov1.y += h * xv[5]; ov1.z += h * xv[6]; ov1.w += h * xv[7];
    out4[o] = ov0; out4[o + 1] = ov1;
}

extern "C" void kernel_launch(void* const* d_in, const int* in_sizes, int n_in,
                              void* d_out, int out_size, void* d_ws, size_t ws_size,
                              hipStream_t stream) {
    const float* x       = (const float*)d_in[0];
    const float* ef      = (const float*)d_in[1];
    const float* hopwise = (const float*)d_in[2];
    const int*   eidx    = (const int*)d_in[3];

    const int E = in_sizes[3] / 2;
    const int D = in_sizes[1] / E;          // 96
    const int N = in_sizes[0] / D;          // 50000
    const int K = in_sizes[2] - 1;          // 3
    const int NC12 = N * CHH;               // node-chunks (12 per node)

    const int* row = eidx;
    const int* col = eidx + E;
    float* out = (float*)d_out;

    // Workspace layout (N even, E multiple of 4 -> 16B alignment holds)
    char* w = (char*)d_ws;
    int*    deg    = (int*)w;     w += (size_t)N * 4;
    int*    starts = (int*)w;     w += (size_t)(N + 8) * 4;
    int*    cursor = (int*)w;     w += (size_t)N * 4;
    int*    eids   = (int*)w;     w += (size_t)E * 4;
    float*  deginv = (float*)w;   w += (size_t)N * 4;
    int*    bsums  = (int*)w;     w += 256 * 4;
    float2* edat   = (float2*)w;  w += (size_t)E * 8;
    float*  bvec   = (float*)w;   w += (size_t)N * D * 4;   // f32 node-major
    h8*     xh     = (h8*)w;      w += (size_t)N * D * 2;   // fp16 x
    h8*     bufh0  = (h8*)w;      w += (size_t)N * D * 2;   // fp16 x1/x3
    h8*     bufh1  = (h8*)w;      /* w += N*D*2 */          // fp16 x2

    const int BT = 256;
    const int nScanBlocks = (N + 1023) / 1024;

    // CSR build
    hipMemsetAsync(deg, 0, (size_t)N * sizeof(int), stream);
    deg_kernel<<<(E + BT - 1) / BT, BT, 0, stream>>>(col, deg, E);
    deginv_kernel<<<(N + BT - 1) / BT, BT, 0, stream>>>(deg, deginv, N);
    scan1_kernel<<<nScanBlocks, 256, 0, stream>>>(deg, starts, bsums, N);
    scan2_kernel<<<1, 64, 0, stream>>>(bsums, nScanBlocks, starts, N, E);
    scan3_kernel<<<nScanBlocks, 256, 0, stream>>>(starts, cursor, bsums, N);
    fill_kernel<<<(E + BT - 1) / BT, BT, 0, stream>>>(col, row, deginv, cursor, eids, edat, E);
    cvt_kernel<<<(NC12 + 255) / 256, 256, 0, stream>>>((const float4*)x, xh, NC12);

    // Fused hop 1 (+ b computation + out init)
    int hopBlocks = (NC12 + 255) / 256;
    hop1_kernel<<<hopBlocks, 256, 0, stream>>>(starts, edat, eids, (const float4*)ef,
                                               xh, (const float4*)x, (float4*)bvec,
                                               bufh0, (float4*)out, hopwise, NC12);

    // hops 2..K
    const h8* xcur = bufh0;
    for (int hop = 2; hop <= K; ++hop) {
        h8* xnext = (xcur == bufh0) ? bufh1 : bufh0;
        int writeNext = (hop < K) ? 1 : 0;
        hop_kernel<<<hopBlocks, 256, 0, stream>>>(starts, edat, xcur, (const float4*)bvec,
                                                  xnext, (float4*)out, hopwise, hop,
                                                  writeNext, NC12);
        xcur = xnext;
    }
}